// Round 2
// baseline (718.395 us; speedup 1.0000x reference)
//
#include <hip/hip_runtime.h>

#define CAP 8192
#define NENV 64
#define DIM 256
#define KSEL 10

constexpr float EPS_C    = 0.001f;
constexpr float MIN_DIST = 0.008f;
constexpr float MAX_SIM  = 2.0f;
constexpr float C_CONST  = 1.0f;
constexpr float L_CLIP   = 5.0f;
constexpr float BIG      = 1e30f;

// ---------------------------------------------------------------------------
// Kernel 1: squared distances di[env][c] = ||obs[env] - data[c,env,:]||^2
// grid = (32, 64), block = 256 (4 waves). Each wave handles one c at a time:
// 64 lanes x float4 = 256 floats = whole row, coalesced 1KiB load.
// ---------------------------------------------------------------------------
__global__ __launch_bounds__(256) void dist_kernel(
    const float* __restrict__ obs,
    const float* __restrict__ data,
    const int*   __restrict__ n_in,
    float*       __restrict__ di)
{
    const int env  = blockIdx.y;
    const int lane = threadIdx.x & 63;
    const int wave = threadIdx.x >> 6;
    const int nvalid = n_in[env];

    const float4 o4 = *reinterpret_cast<const float4*>(obs + env * DIM + lane * 4);

    const int c_base = blockIdx.x * 256;
    #pragma unroll 4
    for (int it = 0; it < 64; ++it) {
        const int c = c_base + it * 4 + wave;
        const float4 d4 = *reinterpret_cast<const float4*>(
            data + (size_t)c * (NENV * DIM) + env * DIM + lane * 4);
        const float dx = o4.x - d4.x;
        const float dy = o4.y - d4.y;
        const float dz = o4.z - d4.z;
        const float dw = o4.w - d4.w;
        float s = dx * dx + dy * dy + dz * dz + dw * dw;
        #pragma unroll
        for (int m = 32; m >= 1; m >>= 1) s += __shfl_xor(s, m, 64);
        if (lane == 0) di[env * CAP + c] = (c < nvalid) ? s : BIG;
    }
}

// ---------------------------------------------------------------------------
// Kernel 2: per-env top-10 smallest (ascending) via 10 iterative min-extracts.
// One block per env, row staged in LDS (32 KiB).
// ---------------------------------------------------------------------------
__global__ __launch_bounds__(256) void topk_kernel(
    const float* __restrict__ di,
    float*       __restrict__ dk)
{
    __shared__ float sh[CAP];
    __shared__ float rval[256];
    __shared__ int   ridx[256];

    const int env = blockIdx.x;
    const int t   = threadIdx.x;

    for (int i = t; i < CAP; i += 256) sh[i] = di[env * CAP + i];
    __syncthreads();

    for (int j = 0; j < KSEL; ++j) {
        float best = BIG;
        int   bidx = CAP;
        for (int i = t; i < CAP; i += 256) {
            const float v = sh[i];
            if (v < best || (v == best && i < bidx)) { best = v; bidx = i; }
        }
        rval[t] = best;
        ridx[t] = bidx;
        __syncthreads();
        for (int sstep = 128; sstep >= 1; sstep >>= 1) {
            if (t < sstep) {
                const float v  = rval[t + sstep];
                const int   ix = ridx[t + sstep];
                if (v < rval[t] || (v == rval[t] && ix < ridx[t])) {
                    rval[t] = v;
                    ridx[t] = ix;
                }
            }
            __syncthreads();
        }
        if (t == 0) {
            dk[env * KSEL + j] = rval[0];
            if (ridx[0] < CAP) sh[ridx[0]] = BIG;
        }
        __syncthreads();
    }
}

// ---------------------------------------------------------------------------
// Kernel 3: cross-env avg + final per-env formula. 1 block, 1 wave (64 lanes),
// lane n = env n.
// ---------------------------------------------------------------------------
__global__ __launch_bounds__(64) void final_kernel(
    const float* __restrict__ dk,
    const int*   __restrict__ n_in,
    const float* __restrict__ r_rnd,
    float*       __restrict__ out)
{
    const int n = threadIdx.x;  // 0..63
    const bool valid = n_in[n] >= KSEL;

    float d[KSEL];
    #pragma unroll
    for (int j = 0; j < KSEL; ++j) d[j] = valid ? dk[n * KSEL + j] : 0.0f;

    const float maxd = d[KSEL - 1];
    float cnt = valid ? 1.0f : 0.0f;
    float sm  = valid ? maxd : 0.0f;
    #pragma unroll
    for (int m = 32; m >= 1; m >>= 1) {
        cnt += __shfl_xor(cnt, m, 64);
        sm  += __shfl_xor(sm, m, 64);
    }

    const float avg   = (cnt > 0.0f) ? (sm / fmaxf(cnt, 1.0f)) : 0.0f;
    const float denom = (avg > 1e-5f) ? avg : 1.0f;

    float ssum = 0.0f;
    #pragma unroll
    for (int j = 0; j < KSEL; ++j) {
        const float dd = fmaxf(d[j] / denom - MIN_DIST, 0.0f);
        ssum += EPS_C / (dd + EPS_C);
    }
    const float s = sqrtf(C_CONST + ssum);
    const float r = (s > MAX_SIM) ? 0.0f : 1.0f / s;
    const float mod = fminf(fmaxf(r_rnd[n], 1.0f), L_CLIP);
    out[n] = r * mod;
}

// ---------------------------------------------------------------------------
extern "C" void kernel_launch(void* const* d_in, const int* in_sizes, int n_in_cnt,
                              void* d_out, int out_size, void* d_ws, size_t ws_size,
                              hipStream_t stream)
{
    const float* obs   = (const float*)d_in[0];
    const float* data  = (const float*)d_in[1];
    const float* r_rnd = (const float*)d_in[2];
    const int*   n_in  = (const int*)d_in[3];
    float* out = (float*)d_out;

    float* di = (float*)d_ws;          // NENV*CAP floats = 2 MiB
    float* dk = di + NENV * CAP;       // NENV*KSEL floats

    dist_kernel <<<dim3(32, NENV), 256, 0, stream>>>(obs, data, n_in, di);
    topk_kernel <<<NENV, 256, 0, stream>>>(di, dk);
    final_kernel<<<1, 64, 0, stream>>>(dk, n_in, r_rnd, out);
}